// Round 1
// baseline (31294.864 us; speedup 1.0000x reference)
//
#include <hip/hip_runtime.h>
#include <math.h>

#define BATCH  8192
#define HIDDEN 512
#define VOCAB  128
#define NSTEP  127   // SEQ_LEN - 1
#define OUTROW (NSTEP * VOCAB)   // 16256 floats per batch row of output

__device__ __forceinline__ float sigmoidf_(float x) {
    return 1.0f / (1.0f + expf(-x));
}

__global__ __launch_bounds__(256) void init_tok_kernel(int* __restrict__ tok) {
    int i = blockIdx.x * 256 + threadIdx.x;
    if (i < BATCH) tok[i] = 0;
}

// c0 = relu(z @ W_cz^T + b_cz). M=8192 N=512 K=512, NT layout, 128x128 tiles.
__global__ __launch_bounds__(256) void c0_kernel(
    const float* __restrict__ z, const float* __restrict__ Wcz,
    const float* __restrict__ bcz, float* __restrict__ c)
{
    __shared__ float As[16][128];
    __shared__ float Bs[16][128];
    const int m0 = blockIdx.x * 128;
    const int n0 = blockIdx.y * 128;
    const int tid = threadIdx.x;
    const int ty = tid >> 4, tx = tid & 15;

    float acc[8][8];
#pragma unroll
    for (int i = 0; i < 8; ++i)
#pragma unroll
        for (int j = 0; j < 8; ++j) acc[i][j] = 0.f;

    for (int kc = 0; kc < HIDDEN; kc += 16) {
#pragma unroll
        for (int i = 0; i < 2; ++i) {
            int id = tid * 2 + i;          // 0..511 float4 slots
            int row = id >> 2;             // 0..127
            int kq = (id & 3) * 4;         // 0,4,8,12
            float4 av = *(const float4*)(z + (size_t)(m0 + row) * HIDDEN + kc + kq);
            As[kq + 0][row] = av.x; As[kq + 1][row] = av.y;
            As[kq + 2][row] = av.z; As[kq + 3][row] = av.w;
            float4 bv = *(const float4*)(Wcz + (size_t)(n0 + row) * HIDDEN + kc + kq);
            Bs[kq + 0][row] = bv.x; Bs[kq + 1][row] = bv.y;
            Bs[kq + 2][row] = bv.z; Bs[kq + 3][row] = bv.w;
        }
        __syncthreads();
#pragma unroll 4
        for (int k = 0; k < 16; ++k) {
            float a[8], b[8];
            *(float4*)&a[0] = *(const float4*)&As[k][ty * 8];
            *(float4*)&a[4] = *(const float4*)&As[k][ty * 8 + 4];
            *(float4*)&b[0] = *(const float4*)&Bs[k][tx * 8];
            *(float4*)&b[4] = *(const float4*)&Bs[k][tx * 8 + 4];
#pragma unroll
            for (int i = 0; i < 8; ++i)
#pragma unroll
                for (int j = 0; j < 8; ++j)
                    acc[i][j] = fmaf(a[i], b[j], acc[i][j]);
        }
        __syncthreads();
    }
#pragma unroll
    for (int i = 0; i < 8; ++i) {
        int m = m0 + ty * 8 + i;
#pragma unroll
        for (int j = 0; j < 8; ++j) {
            int n = n0 + tx * 8 + j;
            c[(size_t)m * HIDDEN + n] = fmaxf(acc[i][j] + bcz[n], 0.f);
        }
    }
}

// One LSTM step, fused: gates = W_ih[:,tok] + h @ W_hh^T + b; activations;
// c,h update. Block tile: 128 batch rows x 32 hidden cols x 4 gates (=128 N).
// Local col index c: gate = c & 3, jj_local = c >> 2  -> W row = gate*512 + jj0 + jj_local.
__global__ __launch_bounds__(256) void lstm_step_kernel(
    const float* __restrict__ h_in, float* __restrict__ c,
    const int* __restrict__ tok,
    const float* __restrict__ W_ih, const float* __restrict__ W_hh,
    const float* __restrict__ b_ih, const float* __restrict__ b_hh,
    float* __restrict__ h_out)
{
    __shared__ float As[16][128];
    __shared__ float Bs[16][128];
    const int m0  = blockIdx.x * 128;
    const int jj0 = blockIdx.y * 32;
    const int tid = threadIdx.x;
    const int ty = tid >> 4, tx = tid & 15;

    float acc[8][8];
#pragma unroll
    for (int i = 0; i < 8; ++i)
#pragma unroll
        for (int j = 0; j < 8; ++j) acc[i][j] = 0.f;

    for (int kc = 0; kc < HIDDEN; kc += 16) {
#pragma unroll
        for (int i = 0; i < 2; ++i) {
            int id = tid * 2 + i;
            int row = id >> 2;             // 0..127
            int kq = (id & 3) * 4;
            float4 av = *(const float4*)(h_in + (size_t)(m0 + row) * HIDDEN + kc + kq);
            As[kq + 0][row] = av.x; As[kq + 1][row] = av.y;
            As[kq + 2][row] = av.z; As[kq + 3][row] = av.w;
            int gate = row & 3;
            int jjl  = row >> 2;
            int wrow = gate * HIDDEN + jj0 + jjl;
            float4 bv = *(const float4*)(W_hh + (size_t)wrow * HIDDEN + kc + kq);
            Bs[kq + 0][row] = bv.x; Bs[kq + 1][row] = bv.y;
            Bs[kq + 2][row] = bv.z; Bs[kq + 3][row] = bv.w;
        }
        __syncthreads();
#pragma unroll 4
        for (int k = 0; k < 16; ++k) {
            float a[8], b[8];
            *(float4*)&a[0] = *(const float4*)&As[k][ty * 8];
            *(float4*)&a[4] = *(const float4*)&As[k][ty * 8 + 4];
            *(float4*)&b[0] = *(const float4*)&Bs[k][tx * 8];
            *(float4*)&b[4] = *(const float4*)&Bs[k][tx * 8 + 4];
#pragma unroll
            for (int i = 0; i < 8; ++i)
#pragma unroll
                for (int j = 0; j < 8; ++j)
                    acc[i][j] = fmaf(a[i], b[j], acc[i][j]);
        }
        __syncthreads();
    }

    // epilogue: per local col j: gate = (tx*8+j)&3 = j&3, jj = jj0 + tx*2 + (j>>2)
    float bias[8];
    int   wih_off[8];
#pragma unroll
    for (int j = 0; j < 8; ++j) {
        int col  = tx * 8 + j;
        int gate = col & 3;
        int jj   = jj0 + (col >> 2);
        int wr   = gate * HIDDEN + jj;
        bias[j]    = b_ih[wr] + b_hh[wr];
        wih_off[j] = wr * VOCAB;
    }
    const int row0 = m0 + ty * 8;
#pragma unroll
    for (int r = 0; r < 8; ++r) {
        int m  = row0 + r;
        int tk = tok[m];
#pragma unroll
        for (int q = 0; q < 2; ++q) {
            float iv = acc[r][q * 4 + 0] + bias[q * 4 + 0] + W_ih[wih_off[q * 4 + 0] + tk];
            float fv = acc[r][q * 4 + 1] + bias[q * 4 + 1] + W_ih[wih_off[q * 4 + 1] + tk];
            float gv = acc[r][q * 4 + 2] + bias[q * 4 + 2] + W_ih[wih_off[q * 4 + 2] + tk];
            float ov = acc[r][q * 4 + 3] + bias[q * 4 + 3] + W_ih[wih_off[q * 4 + 3] + tk];
            float ig = sigmoidf_(iv);
            float fg = sigmoidf_(fv);
            float gg = tanhf(gv);
            float og = sigmoidf_(ov);
            int jj = jj0 + tx * 2 + q;
            size_t idx = (size_t)m * HIDDEN + jj;
            float cn = fg * c[idx] + ig * gg;
            c[idx] = cn;
            h_out[idx] = og * tanhf(cn);
        }
    }
}

// logits = relu(h @ W_fc^T + b_fc); write out[:, t, :]; tok = argmax (ties -> lowest idx).
// Block: 32 batch rows x full 128 vocab. 256 threads (16x16), micro 2x8.
__global__ __launch_bounds__(256) void logits_kernel(
    const float* __restrict__ h, const float* __restrict__ W_fc,
    const float* __restrict__ b_fc, float* __restrict__ out_t,
    int* __restrict__ tok)
{
    __shared__ float As[16][32];
    __shared__ float Bs[16][128];
    __shared__ float redv[32][16];
    __shared__ int   redi[32][16];
    const int m0 = blockIdx.x * 32;
    const int tid = threadIdx.x;
    const int ty = tid >> 4, tx = tid & 15;

    float acc[2][8];
#pragma unroll
    for (int r = 0; r < 2; ++r)
#pragma unroll
        for (int j = 0; j < 8; ++j) acc[r][j] = 0.f;

    for (int kc = 0; kc < HIDDEN; kc += 16) {
        if (tid < 128) {
            int row = tid >> 2;            // 0..31
            int kq = (tid & 3) * 4;
            float4 av = *(const float4*)(h + (size_t)(m0 + row) * HIDDEN + kc + kq);
            As[kq + 0][row] = av.x; As[kq + 1][row] = av.y;
            As[kq + 2][row] = av.z; As[kq + 3][row] = av.w;
        }
#pragma unroll
        for (int i = 0; i < 2; ++i) {
            int id = tid * 2 + i;
            int row = id >> 2;             // vocab row 0..127
            int kq = (id & 3) * 4;
            float4 bv = *(const float4*)(W_fc + (size_t)row * HIDDEN + kc + kq);
            Bs[kq + 0][row] = bv.x; Bs[kq + 1][row] = bv.y;
            Bs[kq + 2][row] = bv.z; Bs[kq + 3][row] = bv.w;
        }
        __syncthreads();
#pragma unroll 4
        for (int k = 0; k < 16; ++k) {
            float a0 = As[k][ty * 2];
            float a1 = As[k][ty * 2 + 1];
            float b[8];
            *(float4*)&b[0] = *(const float4*)&Bs[k][tx * 8];
            *(float4*)&b[4] = *(const float4*)&Bs[k][tx * 8 + 4];
#pragma unroll
            for (int j = 0; j < 8; ++j) {
                acc[0][j] = fmaf(a0, b[j], acc[0][j]);
                acc[1][j] = fmaf(a1, b[j], acc[1][j]);
            }
        }
        __syncthreads();
    }

    float bfc[8];
    *(float4*)&bfc[0] = *(const float4*)&b_fc[tx * 8];
    *(float4*)&bfc[4] = *(const float4*)&b_fc[tx * 8 + 4];
#pragma unroll
    for (int r = 0; r < 2; ++r) {
        int lm = ty * 2 + r;
        int m  = m0 + lm;
        float v[8];
        float best = -INFINITY; int bidx = 0;
#pragma unroll
        for (int j = 0; j < 8; ++j) {
            float x = fmaxf(acc[r][j] + bfc[j], 0.f);
            v[j] = x;
            if (x > best) { best = x; bidx = tx * 8 + j; }
        }
        float* op = out_t + (size_t)m * OUTROW + tx * 8;
        *(float4*)op       = *(const float4*)&v[0];
        *(float4*)(op + 4) = *(const float4*)&v[4];
        redv[lm][tx] = best;
        redi[lm][tx] = bidx;
    }
    __syncthreads();
    if (tid < 32) {
        float best = -INFINITY; int bidx = 0;
#pragma unroll
        for (int x = 0; x < 16; ++x) {
            float vv = redv[tid][x];
            if (vv > best) { best = vv; bidx = redi[tid][x]; }
        }
        tok[m0 + tid] = bidx;
    }
}

extern "C" void kernel_launch(void* const* d_in, const int* in_sizes, int n_in,
                              void* d_out, int out_size, void* d_ws, size_t ws_size,
                              hipStream_t stream)
{
    const float* z    = (const float*)d_in[0];
    const float* W_ih = (const float*)d_in[1];
    const float* W_hh = (const float*)d_in[2];
    const float* b_ih = (const float*)d_in[3];
    const float* b_hh = (const float*)d_in[4];
    const float* W_cz = (const float*)d_in[5];
    const float* b_cz = (const float*)d_in[6];
    const float* W_fc = (const float*)d_in[7];
    const float* b_fc = (const float*)d_in[8];
    float* out = (float*)d_out;

    // workspace layout: c (16MB) | h0 (16MB) | h1 (16MB) | tok (32KB)
    float* c  = (float*)d_ws;
    float* h0 = c  + (size_t)BATCH * HIDDEN;
    float* h1 = h0 + (size_t)BATCH * HIDDEN;
    int*  tokp = (int*)(h1 + (size_t)BATCH * HIDDEN);

    init_tok_kernel<<<BATCH / 256, 256, 0, stream>>>(tokp);
    c0_kernel<<<dim3(BATCH / 128, HIDDEN / 128), 256, 0, stream>>>(z, W_cz, b_cz, c);

    for (int t = 0; t < NSTEP; ++t) {
        const float* h_in = (t == 0) ? z : ((t & 1) ? h0 : h1);
        float* h_out = (t & 1) ? h1 : h0;
        lstm_step_kernel<<<dim3(BATCH / 128, HIDDEN / 32), 256, 0, stream>>>(
            h_in, c, tokp, W_ih, W_hh, b_ih, b_hh, h_out);
        logits_kernel<<<BATCH / 32, 256, 0, stream>>>(
            h_out, W_fc, b_fc, out + (size_t)t * VOCAB, tokp);
    }
}

// Round 2
// 15357.135 us; speedup vs baseline: 2.0378x; 2.0378x over previous
//
#include <hip/hip_runtime.h>
#include <math.h>
#include <stdint.h>

#define BATCH  8192
#define HIDDEN 512
#define VOCAB  128
#define NSTEP  127   // SEQ_LEN - 1
#define OUTROW (NSTEP * VOCAB)
#define NG     2048  // 4*HIDDEN gate columns

using half8  = __attribute__((ext_vector_type(8))) _Float16;
using half4  = __attribute__((ext_vector_type(4))) _Float16;
using float4v = __attribute__((ext_vector_type(4))) float;

#define GLD16(g, l) __builtin_amdgcn_global_load_lds( \
    (const __attribute__((address_space(1))) void*)(g), \
    (__attribute__((address_space(3))) void*)(l), 16, 0, 0)

__device__ __forceinline__ float sigmoidf_(float x) {
    return 1.0f / (1.0f + expf(-x));
}

// permuted gate-column index -> original W row (gate*512 + jj)
// n' = bn*128 + wv*64 + gate*16 + jjl  with jj = bn*32 + wv*16 + jjl
__device__ __forceinline__ int orig_row_of(int np) {
    int bn = np >> 7, cc = np & 127;
    int wv = cc >> 6, cw = cc & 63;
    int gate = cw >> 4, jjl = cw & 15;
    int jj = bn * 32 + wv * 16 + jjl;
    return gate * HIDDEN + jj;
}

__global__ __launch_bounds__(256) void init_tok_kernel(int* __restrict__ tok) {
    int i = blockIdx.x * 256 + threadIdx.x;
    if (i < BATCH) tok[i] = 0;
}

// split W_hh (permuted rows) into fp16 hi/lo at scale 2048
__global__ __launch_bounds__(256) void prep_whh_kernel(
    const float* __restrict__ Whh, _Float16* __restrict__ wh, _Float16* __restrict__ wl)
{
    int np = blockIdx.x;               // 0..2047 permuted row
    int orig = orig_row_of(np);
    for (int k = threadIdx.x; k < HIDDEN; k += 256) {
        float w = Whh[(size_t)orig * HIDDEN + k] * 2048.0f;
        _Float16 h = (_Float16)w;
        wh[(size_t)np * HIDDEN + k] = h;
        wl[(size_t)np * HIDDEN + k] = (_Float16)(w - (float)h);
    }
}

// Wih_T[v][n'] = W_ih[orig(n')][v]; bcomb[n'] = b_ih[orig]+b_hh[orig]
__global__ __launch_bounds__(128) void prep_wih_kernel(
    const float* __restrict__ Wih, const float* __restrict__ bih,
    const float* __restrict__ bhh, float* __restrict__ wihT, float* __restrict__ bcomb)
{
    int np = blockIdx.x;               // 0..2047
    int orig = orig_row_of(np);
    int v = threadIdx.x;               // 0..127
    wihT[(size_t)v * NG + np] = Wih[(size_t)orig * VOCAB + v];
    if (v == 0) bcomb[np] = bih[orig] + bhh[orig];
}

// split z into fp16 hi/lo at scale 2048 (initial h)
__global__ __launch_bounds__(256) void prep_z_kernel(
    const float* __restrict__ z, _Float16* __restrict__ zh, _Float16* __restrict__ zl)
{
    int i = blockIdx.x * 256 + threadIdx.x;    // float4 index
    float4 v = ((const float4*)z)[i];
    float s0 = v.x * 2048.f, s1 = v.y * 2048.f, s2 = v.z * 2048.f, s3 = v.w * 2048.f;
    _Float16 h0 = (_Float16)s0, h1 = (_Float16)s1, h2 = (_Float16)s2, h3 = (_Float16)s3;
    half4 H = {h0, h1, h2, h3};
    half4 L = {(_Float16)(s0 - (float)h0), (_Float16)(s1 - (float)h1),
               (_Float16)(s2 - (float)h2), (_Float16)(s3 - (float)h3)};
    ((half4*)zh)[i] = H;
    ((half4*)zl)[i] = L;
}

// c0 = relu(z @ W_cz^T + b_cz), fp32 128x128 tiles (runs once)
__global__ __launch_bounds__(256) void c0_kernel(
    const float* __restrict__ z, const float* __restrict__ Wcz,
    const float* __restrict__ bcz, float* __restrict__ c)
{
    __shared__ float As[16][128];
    __shared__ float Bs[16][128];
    const int m0 = blockIdx.x * 128;
    const int n0 = blockIdx.y * 128;
    const int tid = threadIdx.x;
    const int ty = tid >> 4, tx = tid & 15;

    float acc[8][8];
#pragma unroll
    for (int i = 0; i < 8; ++i)
#pragma unroll
        for (int j = 0; j < 8; ++j) acc[i][j] = 0.f;

    for (int kc = 0; kc < HIDDEN; kc += 16) {
#pragma unroll
        for (int i = 0; i < 2; ++i) {
            int id = tid * 2 + i;
            int row = id >> 2;
            int kq = (id & 3) * 4;
            float4 av = *(const float4*)(z + (size_t)(m0 + row) * HIDDEN + kc + kq);
            As[kq + 0][row] = av.x; As[kq + 1][row] = av.y;
            As[kq + 2][row] = av.z; As[kq + 3][row] = av.w;
            float4 bv = *(const float4*)(Wcz + (size_t)(n0 + row) * HIDDEN + kc + kq);
            Bs[kq + 0][row] = bv.x; Bs[kq + 1][row] = bv.y;
            Bs[kq + 2][row] = bv.z; Bs[kq + 3][row] = bv.w;
        }
        __syncthreads();
#pragma unroll 4
        for (int k = 0; k < 16; ++k) {
            float a[8], b[8];
            *(float4*)&a[0] = *(const float4*)&As[k][ty * 8];
            *(float4*)&a[4] = *(const float4*)&As[k][ty * 8 + 4];
            *(float4*)&b[0] = *(const float4*)&Bs[k][tx * 8];
            *(float4*)&b[4] = *(const float4*)&Bs[k][tx * 8 + 4];
#pragma unroll
            for (int i = 0; i < 8; ++i)
#pragma unroll
                for (int j = 0; j < 8; ++j)
                    acc[i][j] = fmaf(a[i], b[j], acc[i][j]);
        }
        __syncthreads();
    }
#pragma unroll
    for (int i = 0; i < 8; ++i) {
        int m = m0 + ty * 8 + i;
#pragma unroll
        for (int j = 0; j < 8; ++j) {
            int n = n0 + tx * 8 + j;
            c[(size_t)m * HIDDEN + n] = fmaxf(acc[i][j] + bcz[n], 0.f);
        }
    }
}

// Fused LSTM step: fp16x3 split MFMA GEMM (h @ W_hh^T, permuted cols) + one-hot
// W_ih gather + bias + activations + c/h update. Block 128(M)x128(N'), 4 waves
// 2x2, wave tile 64x64 via 4x4 of 16x16x32 MFMA. Gates of one jj live in one lane.
__global__ __launch_bounds__(256) void lstm_mfma_kernel(
    const _Float16* __restrict__ hin_h, const _Float16* __restrict__ hin_l,
    const _Float16* __restrict__ whh_h, const _Float16* __restrict__ whh_l,
    const float* __restrict__ wihT, const float* __restrict__ bcomb,
    const int* __restrict__ tok, float* __restrict__ c,
    _Float16* __restrict__ hout_h, _Float16* __restrict__ hout_l)
{
    __shared__ _Float16 As_h[128][32];
    __shared__ _Float16 As_l[128][32];
    __shared__ _Float16 Bs_h[128][32];
    __shared__ _Float16 Bs_l[128][32];

    const int tid  = threadIdx.x;
    const int wid  = tid >> 6, lane = tid & 63;
    const int wm   = wid >> 1, wn = wid & 1;
    const int m0   = blockIdx.x * 128;
    const int n0   = blockIdx.y * 128;

    float4v acc[4][4];
#pragma unroll
    for (int i = 0; i < 4; ++i)
#pragma unroll
        for (int j = 0; j < 4; ++j) acc[i][j] = (float4v){0.f, 0.f, 0.f, 0.f};

    // staging addresses: wave wid stages rows [wid*32, wid*32+32) of each tile
    const int r0    = wid * 32;
    const int srow  = lane >> 2;       // 0..15
    const int squad = lane & 3;        // 0..3 -> k-offset quad*8 (f16)
    const size_t aoff  = (size_t)(m0 + r0 + srow) * HIDDEN + squad * 8;
    const size_t aoff2 = aoff + (size_t)16 * HIDDEN;
    const size_t boff  = (size_t)(n0 + r0 + srow) * HIDDEN + squad * 8;
    const size_t boff2 = boff + (size_t)16 * HIDDEN;

    const int ar = wm * 64 + (lane & 15);
    const int br = wn * 64 + (lane & 15);
    const int kk = (lane >> 4) * 8;

    for (int kc = 0; kc < HIDDEN; kc += 32) {
        GLD16(hin_h + aoff  + kc, &As_h[r0][0]);
        GLD16(hin_h + aoff2 + kc, &As_h[r0 + 16][0]);
        GLD16(hin_l + aoff  + kc, &As_l[r0][0]);
        GLD16(hin_l + aoff2 + kc, &As_l[r0 + 16][0]);
        GLD16(whh_h + boff  + kc, &Bs_h[r0][0]);
        GLD16(whh_h + boff2 + kc, &Bs_h[r0 + 16][0]);
        GLD16(whh_l + boff  + kc, &Bs_l[r0][0]);
        GLD16(whh_l + boff2 + kc, &Bs_l[r0 + 16][0]);
        __syncthreads();

        half8 ah[4], al[4], bh[4], bl[4];
#pragma unroll
        for (int j = 0; j < 4; ++j) {
            ah[j] = *(const half8*)&As_h[ar + j * 16][kk];
            al[j] = *(const half8*)&As_l[ar + j * 16][kk];
            bh[j] = *(const half8*)&Bs_h[br + j * 16][kk];
            bl[j] = *(const half8*)&Bs_l[br + j * 16][kk];
        }
#pragma unroll
        for (int i = 0; i < 4; ++i)
#pragma unroll
            for (int j = 0; j < 4; ++j) {
                acc[i][j] = __builtin_amdgcn_mfma_f32_16x16x32_f16(ah[i], bh[j], acc[i][j], 0, 0, 0);
                acc[i][j] = __builtin_amdgcn_mfma_f32_16x16x32_f16(ah[i], bl[j], acc[i][j], 0, 0, 0);
                acc[i][j] = __builtin_amdgcn_mfma_f32_16x16x32_f16(al[i], bh[j], acc[i][j], 0, 0, 0);
            }
        __syncthreads();
    }

    // epilogue: lane holds all 4 gates for jj = by*32 + wn*16 + (lane&15)
    const float INV22 = 1.0f / 4194304.0f;   // 2^-22
    const int t  = lane & 15, qr = lane >> 4;
    const int jj = blockIdx.y * 32 + wn * 16 + t;
    const int colb = n0 + wn * 64 + t;
    float bias[4];
    int   col[4];
#pragma unroll
    for (int j = 0; j < 4; ++j) {
        col[j]  = colb + j * 16;
        bias[j] = bcomb[col[j]];
    }
#pragma unroll
    for (int i = 0; i < 4; ++i) {
        int mb = m0 + wm * 64 + i * 16 + qr * 4;
#pragma unroll
        for (int r = 0; r < 4; ++r) {
            int m  = mb + r;
            int tk = tok[m];
            const float* wv = wihT + (size_t)tk * NG;
            float iv = acc[i][0][r] * INV22 + bias[0] + wv[col[0]];
            float fv = acc[i][1][r] * INV22 + bias[1] + wv[col[1]];
            float gv = acc[i][2][r] * INV22 + bias[2] + wv[col[2]];
            float ov = acc[i][3][r] * INV22 + bias[3] + wv[col[3]];
            float ig = sigmoidf_(iv);
            float fg = sigmoidf_(fv);
            float gg = tanhf(gv);
            float og = sigmoidf_(ov);
            size_t ci = (size_t)m * HIDDEN + jj;
            float cn = fg * c[ci] + ig * gg;
            c[ci] = cn;
            float hn = og * tanhf(cn);
            float hs = hn * 2048.f;
            _Float16 hh = (_Float16)hs;
            hout_h[ci] = hh;
            hout_l[ci] = (_Float16)(hs - (float)hh);
        }
    }
}

// logits = relu(h @ W_fc^T + b_fc) from split h; write out[:,t,:]; tok = argmax
__global__ __launch_bounds__(256) void logits_kernel(
    const _Float16* __restrict__ hh, const _Float16* __restrict__ hl,
    const float* __restrict__ W_fc, const float* __restrict__ b_fc,
    float* __restrict__ out_t, int* __restrict__ tok)
{
    __shared__ float As[16][32];
    __shared__ float Bs[16][128];
    __shared__ float redv[32][16];
    __shared__ int   redi[32][16];
    const int m0 = blockIdx.x * 32;
    const int tid = threadIdx.x;
    const int ty = tid >> 4, tx = tid & 15;

    float acc[2][8];
#pragma unroll
    for (int r = 0; r < 2; ++r)
#pragma unroll
        for (int j = 0; j < 8; ++j) acc[r][j] = 0.f;

    const float RS = 1.0f / 2048.0f;
    for (int kc = 0; kc < HIDDEN; kc += 16) {
        if (tid < 128) {
            int row = tid >> 2;
            int kq = (tid & 3) * 4;
            size_t off = (size_t)(m0 + row) * HIDDEN + kc + kq;
            half4 hv = *(const half4*)(hh + off);
            half4 lv = *(const half4*)(hl + off);
#pragma unroll
            for (int j = 0; j < 4; ++j)
                As[kq + j][row] = ((float)hv[j] + (float)lv[j]) * RS;
        }
#pragma unroll
        for (int i = 0; i < 2; ++i) {
            int id = tid * 2 + i;
            int row = id >> 2;
            int kq = (id & 3) * 4;
            float4 bv = *(const float4*)(W_fc + (size_t)row * HIDDEN + kc + kq);
            Bs[kq + 0][row] = bv.x; Bs[kq + 1][row] = bv.y;
            Bs[kq + 2][row] = bv.z; Bs[kq + 3][row] = bv.w;
        }
        __syncthreads();
#pragma unroll 4
        for (int k = 0; k < 16; ++k) {
            float a0 = As[k][ty * 2];
            float a1 = As[k][ty * 2 + 1];
            float b[8];
            *(float4*)&b[0] = *(const float4*)&Bs[k][tx * 8];
            *(float4*)&b[4] = *(const float4*)&Bs[k][tx * 8 + 4];
#pragma unroll
            for (int j = 0; j < 8; ++j) {
                acc[0][j] = fmaf(a0, b[j], acc[0][j]);
                acc[1][j] = fmaf(a1, b[j], acc[1][j]);
            }
        }
        __syncthreads();
    }

    float bfc[8];
    *(float4*)&bfc[0] = *(const float4*)&b_fc[tx * 8];
    *(float4*)&bfc[4] = *(const float4*)&b_fc[tx * 8 + 4];
#pragma unroll
    for (int r = 0; r < 2; ++r) {
        int lm = ty * 2 + r;
        int m  = m0 + lm;
        float v[8];
        float best = -INFINITY; int bidx = 0;
#pragma unroll
        for (int j = 0; j < 8; ++j) {
            float x = fmaxf(acc[r][j] + bfc[j], 0.f);
            v[j] = x;
            if (x > best) { best = x; bidx = tx * 8 + j; }
        }
        float* op = out_t + (size_t)m * OUTROW + tx * 8;
        *(float4*)op       = *(const float4*)&v[0];
        *(float4*)(op + 4) = *(const float4*)&v[4];
        redv[lm][tx] = best;
        redi[lm][tx] = bidx;
    }
    __syncthreads();
    if (tid < 32) {
        float best = -INFINITY; int bidx = 0;
#pragma unroll
        for (int x = 0; x < 16; ++x) {
            float vv = redv[tid][x];
            if (vv > best) { best = vv; bidx = redi[tid][x]; }
        }
        tok[m0 + tid] = bidx;
    }
}

extern "C" void kernel_launch(void* const* d_in, const int* in_sizes, int n_in,
                              void* d_out, int out_size, void* d_ws, size_t ws_size,
                              hipStream_t stream)
{
    const float* z    = (const float*)d_in[0];
    const float* W_ih = (const float*)d_in[1];
    const float* W_hh = (const float*)d_in[2];
    const float* b_ih = (const float*)d_in[3];
    const float* b_hh = (const float*)d_in[4];
    const float* W_cz = (const float*)d_in[5];
    const float* b_cz = (const float*)d_in[6];
    const float* W_fc = (const float*)d_in[7];
    const float* b_fc = (const float*)d_in[8];
    float* out = (float*)d_out;

    // workspace carve (~54.7 MB)
    uint8_t* p = (uint8_t*)d_ws;
    float* c = (float*)p;            p += (size_t)BATCH * HIDDEN * 4;   // 16 MB
    _Float16* sA_h = (_Float16*)p;   p += (size_t)BATCH * HIDDEN * 2;   // 8 MB
    _Float16* sA_l = (_Float16*)p;   p += (size_t)BATCH * HIDDEN * 2;
    _Float16* sB_h = (_Float16*)p;   p += (size_t)BATCH * HIDDEN * 2;
    _Float16* sB_l = (_Float16*)p;   p += (size_t)BATCH * HIDDEN * 2;
    _Float16* whhh = (_Float16*)p;   p += (size_t)NG * HIDDEN * 2;      // 2 MB
    _Float16* whhl = (_Float16*)p;   p += (size_t)NG * HIDDEN * 2;
    float* wihT  = (float*)p;        p += (size_t)VOCAB * NG * 4;       // 1 MB
    float* bcomb = (float*)p;        p += (size_t)NG * 4;
    int* tokp    = (int*)p;          p += (size_t)BATCH * 4;

    init_tok_kernel<<<BATCH / 256, 256, 0, stream>>>(tokp);
    prep_whh_kernel<<<NG, 256, 0, stream>>>(W_hh, whhh, whhl);
    prep_wih_kernel<<<NG, 128, 0, stream>>>(W_ih, b_ih, b_hh, wihT, bcomb);
    prep_z_kernel<<<(BATCH * HIDDEN / 4) / 256, 256, 0, stream>>>(z, sA_h, sA_l);
    c0_kernel<<<dim3(BATCH / 128, HIDDEN / 128), 256, 0, stream>>>(z, W_cz, b_cz, c);

    for (int t = 0; t < NSTEP; ++t) {
        const _Float16* inh = (t & 1) ? sB_h : sA_h;
        const _Float16* inl = (t & 1) ? sB_l : sA_l;
        _Float16* outh = (t & 1) ? sA_h : sB_h;
        _Float16* outl = (t & 1) ? sA_l : sB_l;
        lstm_mfma_kernel<<<dim3(BATCH / 128, NG / 128), 256, 0, stream>>>(
            inh, inl, whhh, whhl, wihT, bcomb, tokp, c, outh, outl);
        logits_kernel<<<BATCH / 32, 256, 0, stream>>>(
            outh, outl, W_fc, b_fc, out + (size_t)t * VOCAB, tokp);
    }
}

// Round 3
// 8488.506 us; speedup vs baseline: 3.6867x; 1.8092x over previous
//
#include <hip/hip_runtime.h>
#include <math.h>
#include <stdint.h>

#define BATCH  8192
#define HIDDEN 512
#define VOCAB  128
#define NSTEP  127   // SEQ_LEN - 1
#define OUTROW (NSTEP * VOCAB)
#define NG     2048  // 4*HIDDEN gate columns

using half8   = __attribute__((ext_vector_type(8))) _Float16;
using half4   = __attribute__((ext_vector_type(4))) _Float16;
using float4v = __attribute__((ext_vector_type(4))) float;

#define GLD16(g, l) __builtin_amdgcn_global_load_lds( \
    (const __attribute__((address_space(1))) void*)(g), \
    (__attribute__((address_space(3))) void*)(l), 16, 0, 0)

__device__ __forceinline__ float fast_rcp(float x) { return __builtin_amdgcn_rcpf(x); }
__device__ __forceinline__ float fast_sig(float x) { return fast_rcp(1.0f + __expf(-x)); }
__device__ __forceinline__ float fast_tanh(float x) { return 1.0f - 2.0f * fast_rcp(1.0f + __expf(2.0f * x)); }

// permuted gate-column index -> original W row (gate*512 + jj)
// n' = bn*128 + wv*64 + gate*16 + jjl  with jj = bn*32 + wv*16 + jjl
__device__ __forceinline__ int orig_row_of(int np) {
    int bn = np >> 7, cc = np & 127;
    int wv = cc >> 6, cw = cc & 63;
    int gate = cw >> 4, jjl = cw & 15;
    int jj = bn * 32 + wv * 16 + jjl;
    return gate * HIDDEN + jj;
}

__global__ __launch_bounds__(256) void init_tok_kernel(int* __restrict__ tok) {
    int i = blockIdx.x * 256 + threadIdx.x;
    if (i < BATCH) tok[i] = 0;
}

__global__ __launch_bounds__(256) void prep_whh_kernel(
    const float* __restrict__ Whh, _Float16* __restrict__ wh, _Float16* __restrict__ wl)
{
    int np = blockIdx.x;
    int orig = orig_row_of(np);
    for (int k = threadIdx.x; k < HIDDEN; k += 256) {
        float w = Whh[(size_t)orig * HIDDEN + k] * 2048.0f;
        _Float16 h = (_Float16)w;
        wh[(size_t)np * HIDDEN + k] = h;
        wl[(size_t)np * HIDDEN + k] = (_Float16)(w - (float)h);
    }
}

__global__ __launch_bounds__(128) void prep_wih_kernel(
    const float* __restrict__ Wih, const float* __restrict__ bih,
    const float* __restrict__ bhh, float* __restrict__ wihT, float* __restrict__ bcomb)
{
    int np = blockIdx.x;
    int orig = orig_row_of(np);
    int v = threadIdx.x;
    wihT[(size_t)v * NG + np] = Wih[(size_t)orig * VOCAB + v];
    if (v == 0) bcomb[np] = bih[orig] + bhh[orig];
}

__global__ __launch_bounds__(256) void prep_wfc_kernel(
    const float* __restrict__ Wfc, _Float16* __restrict__ wh, _Float16* __restrict__ wl)
{
    int i = blockIdx.x * 256 + threadIdx.x;   // 128*512 = 65536 elems
    float w = Wfc[i] * 2048.0f;
    _Float16 h = (_Float16)w;
    wh[i] = h;
    wl[i] = (_Float16)(w - (float)h);
}

__global__ __launch_bounds__(256) void prep_z_kernel(
    const float* __restrict__ z, _Float16* __restrict__ zh, _Float16* __restrict__ zl)
{
    int i = blockIdx.x * 256 + threadIdx.x;
    float4 v = ((const float4*)z)[i];
    float s0 = v.x * 2048.f, s1 = v.y * 2048.f, s2 = v.z * 2048.f, s3 = v.w * 2048.f;
    _Float16 h0 = (_Float16)s0, h1 = (_Float16)s1, h2 = (_Float16)s2, h3 = (_Float16)s3;
    half4 H = {h0, h1, h2, h3};
    half4 L = {(_Float16)(s0 - (float)h0), (_Float16)(s1 - (float)h1),
               (_Float16)(s2 - (float)h2), (_Float16)(s3 - (float)h3)};
    ((half4*)zh)[i] = H;
    ((half4*)zl)[i] = L;
}

// c0 = relu(z @ W_cz^T + b_cz), fp32 (runs once)
__global__ __launch_bounds__(256) void c0_kernel(
    const float* __restrict__ z, const float* __restrict__ Wcz,
    const float* __restrict__ bcz, float* __restrict__ c)
{
    __shared__ float As[16][128];
    __shared__ float Bs[16][128];
    const int m0 = blockIdx.x * 128;
    const int n0 = blockIdx.y * 128;
    const int tid = threadIdx.x;
    const int ty = tid >> 4, tx = tid & 15;

    float acc[8][8];
#pragma unroll
    for (int i = 0; i < 8; ++i)
#pragma unroll
        for (int j = 0; j < 8; ++j) acc[i][j] = 0.f;

    for (int kc = 0; kc < HIDDEN; kc += 16) {
#pragma unroll
        for (int i = 0; i < 2; ++i) {
            int id = tid * 2 + i;
            int row = id >> 2;
            int kq = (id & 3) * 4;
            float4 av = *(const float4*)(z + (size_t)(m0 + row) * HIDDEN + kc + kq);
            As[kq + 0][row] = av.x; As[kq + 1][row] = av.y;
            As[kq + 2][row] = av.z; As[kq + 3][row] = av.w;
            float4 bv = *(const float4*)(Wcz + (size_t)(n0 + row) * HIDDEN + kc + kq);
            Bs[kq + 0][row] = bv.x; Bs[kq + 1][row] = bv.y;
            Bs[kq + 2][row] = bv.z; Bs[kq + 3][row] = bv.w;
        }
        __syncthreads();
#pragma unroll 4
        for (int k = 0; k < 16; ++k) {
            float a[8], b[8];
            *(float4*)&a[0] = *(const float4*)&As[k][ty * 8];
            *(float4*)&a[4] = *(const float4*)&As[k][ty * 8 + 4];
            *(float4*)&b[0] = *(const float4*)&Bs[k][tx * 8];
            *(float4*)&b[4] = *(const float4*)&Bs[k][tx * 8 + 4];
#pragma unroll
            for (int i = 0; i < 8; ++i)
#pragma unroll
                for (int j = 0; j < 8; ++j)
                    acc[i][j] = fmaf(a[i], b[j], acc[i][j]);
        }
        __syncthreads();
    }
#pragma unroll
    for (int i = 0; i < 8; ++i) {
        int m = m0 + ty * 8 + i;
#pragma unroll
        for (int j = 0; j < 8; ++j) {
            int n = n0 + tx * 8 + j;
            c[(size_t)m * HIDDEN + n] = fmaxf(acc[i][j] + bcz[n], 0.f);
        }
    }
}

// Fused LSTM step. Block 128(M) x 256(N'), 256 threads = 4 waves tiled 1x4,
// wave tile 128x64 (= one full gate group: 4 gates x 16 jj). fp16x3 split MFMA.
// LDS tiles BK=32 halves with XOR-chunk swizzle (conflict-free b128 reads).
__global__ __launch_bounds__(256, 2) void lstm_mfma_kernel(
    const _Float16* __restrict__ hin_h, const _Float16* __restrict__ hin_l,
    const _Float16* __restrict__ whh_h, const _Float16* __restrict__ whh_l,
    const float* __restrict__ wihT, const float* __restrict__ bcomb,
    const int* __restrict__ tok, float* __restrict__ c,
    _Float16* __restrict__ hout_h, _Float16* __restrict__ hout_l)
{
    __shared__ _Float16 As_h[128][32];
    __shared__ _Float16 As_l[128][32];
    __shared__ _Float16 Bs_h[256][32];
    __shared__ _Float16 Bs_l[256][32];

    const int tid  = threadIdx.x;
    const int wid  = tid >> 6, lane = tid & 63;
    const int m0   = blockIdx.x * 128;
    const int n0   = blockIdx.y * 256;

    float4v acc[8][4];
#pragma unroll
    for (int i = 0; i < 8; ++i)
#pragma unroll
        for (int j = 0; j < 4; ++j) acc[i][j] = (float4v){0.f, 0.f, 0.f, 0.f};

    // staging: lane covers row lane>>2, chunk-slot lane&3; source chunk XOR-swizzled
    const int lrow = lane >> 2;
    const int lchk = (lane & 3) ^ ((lane >> 3) & 3);
    const int loff = lrow * HIDDEN + lchk * 8;

    const _Float16* agh = hin_h + (size_t)(m0 + wid * 32) * HIDDEN + loff;
    const _Float16* agl = hin_l + (size_t)(m0 + wid * 32) * HIDDEN + loff;
    const _Float16* bgh = whh_h + (size_t)(n0 + wid * 64) * HIDDEN + loff;
    const _Float16* bgl = whh_l + (size_t)(n0 + wid * 64) * HIDDEN + loff;

    // fragment read setup: row = tile16*16 + t, chunk q = lane>>4, swizzled offset
    const int t = lane & 15, qr = lane >> 4;
    const int qa = (qr ^ ((t >> 1) & 3)) * 8;

    for (int kc = 0; kc < HIDDEN; kc += 32) {
        GLD16(agh + kc,                   &As_h[wid * 32][0]);
        GLD16(agh + kc + 16 * HIDDEN,     &As_h[wid * 32 + 16][0]);
        GLD16(agl + kc,                   &As_l[wid * 32][0]);
        GLD16(agl + kc + 16 * HIDDEN,     &As_l[wid * 32 + 16][0]);
        GLD16(bgh + kc,                   &Bs_h[wid * 64][0]);
        GLD16(bgh + kc + 16 * HIDDEN,     &Bs_h[wid * 64 + 16][0]);
        GLD16(bgh + kc + 32 * HIDDEN,     &Bs_h[wid * 64 + 32][0]);
        GLD16(bgh + kc + 48 * HIDDEN,     &Bs_h[wid * 64 + 48][0]);
        GLD16(bgl + kc,                   &Bs_l[wid * 64][0]);
        GLD16(bgl + kc + 16 * HIDDEN,     &Bs_l[wid * 64 + 16][0]);
        GLD16(bgl + kc + 32 * HIDDEN,     &Bs_l[wid * 64 + 32][0]);
        GLD16(bgl + kc + 48 * HIDDEN,     &Bs_l[wid * 64 + 48][0]);
        __syncthreads();

        half8 bh[4], bl[4];
#pragma unroll
        for (int j = 0; j < 4; ++j) {
            bh[j] = *(const half8*)&Bs_h[wid * 64 + j * 16 + t][qa];
            bl[j] = *(const half8*)&Bs_l[wid * 64 + j * 16 + t][qa];
        }
#pragma unroll
        for (int i = 0; i < 8; ++i) {
            half8 ah = *(const half8*)&As_h[i * 16 + t][qa];
            half8 al = *(const half8*)&As_l[i * 16 + t][qa];
#pragma unroll
            for (int j = 0; j < 4; ++j) {
                acc[i][j] = __builtin_amdgcn_mfma_f32_16x16x32_f16(ah, bh[j], acc[i][j], 0, 0, 0);
                acc[i][j] = __builtin_amdgcn_mfma_f32_16x16x32_f16(ah, bl[j], acc[i][j], 0, 0, 0);
                acc[i][j] = __builtin_amdgcn_mfma_f32_16x16x32_f16(al, bh[j], acc[i][j], 0, 0, 0);
            }
        }
        __syncthreads();
    }

    // epilogue: wave wid covers gate group g; lane t owns jj, all 4 gates in acc[.][0..3]
    const float INV22 = 1.0f / 4194304.0f;   // 2^-22
    const int g  = blockIdx.y * 4 + wid;
    const int jj = (g >> 1) * 32 + (g & 1) * 16 + t;
    const int colb = n0 + wid * 64 + t;
    float bias[4];
    int   col[4];
#pragma unroll
    for (int j = 0; j < 4; ++j) {
        col[j]  = colb + j * 16;
        bias[j] = bcomb[col[j]];
    }
#pragma unroll
    for (int i = 0; i < 8; ++i) {
        int mb = m0 + i * 16 + qr * 4;
#pragma unroll
        for (int r = 0; r < 4; ++r) {
            int m  = mb + r;
            int tk = tok[m];
            const float* wv = wihT + (size_t)tk * NG;
            float iv = acc[i][0][r] * INV22 + bias[0] + wv[col[0]];
            float fv = acc[i][1][r] * INV22 + bias[1] + wv[col[1]];
            float gv = acc[i][2][r] * INV22 + bias[2] + wv[col[2]];
            float ov = acc[i][3][r] * INV22 + bias[3] + wv[col[3]];
            float ig = fast_sig(iv);
            float fg = fast_sig(fv);
            float gg = fast_tanh(gv);
            float og = fast_sig(ov);
            size_t ci = (size_t)m * HIDDEN + jj;
            float cn = fg * c[ci] + ig * gg;
            c[ci] = cn;
            float hn = og * fast_tanh(cn);
            float hs = hn * 2048.f;
            _Float16 hh = (_Float16)hs;
            hout_h[ci] = hh;
            hout_l[ci] = (_Float16)(hs - (float)hh);
        }
    }
}

// logits = relu(h @ W_fc^T + b_fc) via fp16x3 MFMA; write out[:,t,:]; tok = argmax.
// Block 32(M) x 128(N), 128 threads = 2 waves, each wave 16 rows. BK=64, swizzled.
__global__ __launch_bounds__(128) void logits_mfma_kernel(
    const _Float16* __restrict__ hh_, const _Float16* __restrict__ hl_,
    const _Float16* __restrict__ wfc_h, const _Float16* __restrict__ wfc_l,
    const float* __restrict__ b_fc, float* __restrict__ out_t, int* __restrict__ tok)
{
    __shared__ _Float16 Ah[32][64];
    __shared__ _Float16 Al[32][64];
    __shared__ _Float16 Bh[128][64];
    __shared__ _Float16 Bl[128][64];

    const int tid = threadIdx.x;
    const int wid = tid >> 6, lane = tid & 63;
    const int m0  = blockIdx.x * 32;
    const int t   = lane & 15, qr = lane >> 4;

    float4v acc[8];
#pragma unroll
    for (int j = 0; j < 8; ++j) acc[j] = (float4v){0.f, 0.f, 0.f, 0.f};

    // staging: 8 rows per GLD16 (row = lane>>3, chunk-slot lane&7, swizzled source)
    const int lrow = lane >> 3;
    const int lchk = (lane & 7) ^ lrow;
    const int loff = lrow * HIDDEN + lchk * 8;

    // wave0 stages Ah + B rows [0,64); wave1 stages Al + B rows [64,128)
    const _Float16* Ag = (wid == 0 ? hh_ : hl_) + (size_t)m0 * HIDDEN + loff;
    _Float16* Adst = (wid == 0) ? &Ah[0][0] : &Al[0][0];
    const _Float16* Bgh = wfc_h + (size_t)(wid * 64) * HIDDEN + loff;
    const _Float16* Bgl = wfc_l + (size_t)(wid * 64) * HIDDEN + loff;

    const int sa = t & 7;   // fragment swizzle key (row & 7 = t & 7)

    for (int kc = 0; kc < HIDDEN; kc += 64) {
#pragma unroll
        for (int s = 0; s < 4; ++s)
            GLD16(Ag + kc + s * 8 * HIDDEN, Adst + (s * 8) * 64);
#pragma unroll
        for (int s = 0; s < 8; ++s) {
            GLD16(Bgh + kc + s * 8 * HIDDEN, &Bh[wid * 64 + s * 8][0]);
            GLD16(Bgl + kc + s * 8 * HIDDEN, &Bl[wid * 64 + s * 8][0]);
        }
        __syncthreads();
#pragma unroll
        for (int kh = 0; kh < 2; ++kh) {
            int q = kh * 4 + qr;
            int arow = wid * 16 + t;
            half8 a_h = *(const half8*)&Ah[arow][(q ^ sa) * 8];
            half8 a_l = *(const half8*)&Al[arow][(q ^ sa) * 8];
#pragma unroll
            for (int j = 0; j < 8; ++j) {
                half8 b_h = *(const half8*)&Bh[j * 16 + t][(q ^ sa) * 8];
                half8 b_l = *(const half8*)&Bl[j * 16 + t][(q ^ sa) * 8];
                acc[j] = __builtin_amdgcn_mfma_f32_16x16x32_f16(a_h, b_h, acc[j], 0, 0, 0);
                acc[j] = __builtin_amdgcn_mfma_f32_16x16x32_f16(a_h, b_l, acc[j], 0, 0, 0);
                acc[j] = __builtin_amdgcn_mfma_f32_16x16x32_f16(a_l, b_h, acc[j], 0, 0, 0);
            }
        }
        __syncthreads();
    }

    const float INV22 = 1.0f / 4194304.0f;
    float bv[8];
#pragma unroll
    for (int j = 0; j < 8; ++j) bv[j] = b_fc[j * 16 + t];

#pragma unroll
    for (int r = 0; r < 4; ++r) {
        int m = m0 + wid * 16 + qr * 4 + r;
        float vals[8];
        float vbest = -1.0f; int ibest = 0;
#pragma unroll
        for (int j = 0; j < 8; ++j) {
            float x = fmaxf(acc[j][r] * INV22 + bv[j], 0.f);
            vals[j] = x;
            if (x > vbest) { vbest = x; ibest = j * 16 + t; }
        }
        float* op = out_t + (size_t)m * OUTROW;
#pragma unroll
        for (int j = 0; j < 8; ++j) op[j * 16 + t] = vals[j];
        // argmax across the 16 lanes of this quad (first-max tie semantics)
#pragma unroll
        for (int d = 1; d < 16; d <<= 1) {
            float vo = __shfl_xor(vbest, d, 64);
            int   io = __shfl_xor(ibest, d, 64);
            if (vo > vbest || (vo == vbest && io < ibest)) { vbest = vo; ibest = io; }
        }
        if (t == 0) tok[m] = ibest;
    }
}

extern "C" void kernel_launch(void* const* d_in, const int* in_sizes, int n_in,
                              void* d_out, int out_size, void* d_ws, size_t ws_size,
                              hipStream_t stream)
{
    const float* z    = (const float*)d_in[0];
    const float* W_ih = (const float*)d_in[1];
    const float* W_hh = (const float*)d_in[2];
    const float* b_ih = (const float*)d_in[3];
    const float* b_hh = (const float*)d_in[4];
    const float* W_cz = (const float*)d_in[5];
    const float* b_cz = (const float*)d_in[6];
    const float* W_fc = (const float*)d_in[7];
    const float* b_fc = (const float*)d_in[8];
    float* out = (float*)d_out;

    uint8_t* p = (uint8_t*)d_ws;
    float* c = (float*)p;            p += (size_t)BATCH * HIDDEN * 4;   // 16 MB
    _Float16* sA_h = (_Float16*)p;   p += (size_t)BATCH * HIDDEN * 2;   // 8 MB each
    _Float16* sA_l = (_Float16*)p;   p += (size_t)BATCH * HIDDEN * 2;
    _Float16* sB_h = (_Float16*)p;   p += (size_t)BATCH * HIDDEN * 2;
    _Float16* sB_l = (_Float16*)p;   p += (size_t)BATCH * HIDDEN * 2;
    _Float16* whhh = (_Float16*)p;   p += (size_t)NG * HIDDEN * 2;      // 2 MB each
    _Float16* whhl = (_Float16*)p;   p += (size_t)NG * HIDDEN * 2;
    _Float16* wfch = (_Float16*)p;   p += (size_t)VOCAB * HIDDEN * 2;   // 128 KB each
    _Float16* wfcl = (_Float16*)p;   p += (size_t)VOCAB * HIDDEN * 2;
    float* wihT  = (float*)p;        p += (size_t)VOCAB * NG * 4;       // 1 MB
    float* bcomb = (float*)p;        p += (size_t)NG * 4;
    int* tokp    = (int*)p;          p += (size_t)BATCH * 4;

    init_tok_kernel<<<BATCH / 256, 256, 0, stream>>>(tokp);
    prep_whh_kernel<<<NG, 256, 0, stream>>>(W_hh, whhh, whhl);
    prep_wih_kernel<<<NG, 128, 0, stream>>>(W_ih, b_ih, b_hh, wihT, bcomb);
    prep_wfc_kernel<<<(VOCAB * HIDDEN) / 256, 256, 0, stream>>>(W_fc, wfch, wfcl);
    prep_z_kernel<<<(BATCH * HIDDEN / 4) / 256, 256, 0, stream>>>(z, sA_h, sA_l);
    c0_kernel<<<dim3(BATCH / 128, HIDDEN / 128), 256, 0, stream>>>(z, W_cz, b_cz, c);

    for (int t = 0; t < NSTEP; ++t) {
        const _Float16* inh = (t & 1) ? sB_h : sA_h;
        const _Float16* inl = (t & 1) ? sB_l : sA_l;
        _Float16* outh = (t & 1) ? sA_h : sB_h;
        _Float16* outl = (t & 1) ? sA_l : sB_l;
        lstm_mfma_kernel<<<dim3(BATCH / 128, NG / 256), 256, 0, stream>>>(
            inh, inl, whhh, whhl, wihT, bcomb, tokp, c, outh, outl);
        logits_mfma_kernel<<<BATCH / 32, 128, 0, stream>>>(
            outh, outl, wfch, wfcl, b_fc, out + (size_t)t * VOCAB, tokp);
    }
}